// Round 1
// baseline (122.548 us; speedup 1.0000x reference)
//
#include <hip/hip_runtime.h>
#include <math.h>

// SpectralAngleLoss: B=8192 rows, N=256 peaks, 2000 bins.
// Kernel 1: one block per row. LDS histograms (pred, target), then
//           dot / ||p|| / ||t|| reduction in-block -> angle/pi per row.
// Kernel 2: deterministic tree reduction of 8192 row angles -> mean.

#define SAL_NUM_BINS 2000
#define SAL_B 8192
#define SAL_N 256

__global__ __launch_bounds__(256) void sal_row_kernel(
    const float* __restrict__ pred_mz,
    const float* __restrict__ pred_int,
    const float* __restrict__ targ_mz,
    const float* __restrict__ targ_int,
    const float* __restrict__ targ_mask,
    float* __restrict__ row_angle)
{
    __shared__ float ph[SAL_NUM_BINS];
    __shared__ float th[SAL_NUM_BINS];
    const int b = blockIdx.x;
    const int t = threadIdx.x;

    // zero histograms (2000*2 floats, 256 threads -> ~16 iters)
    for (int i = t; i < SAL_NUM_BINS; i += 256) { ph[i] = 0.0f; th[i] = 0.0f; }
    __syncthreads();

    // scatter this row's peaks (N==blockDim.x==256: one peak/thread)
    const int base = b * SAL_N;
    {
        float pmz = pred_mz[base + t];
        float pin = pred_int[base + t];
        float tmz = targ_mz[base + t];
        float tin = targ_int[base + t] * targ_mask[base + t];
        int pb = (int)(pmz * 2000.0f);
        pb = min(max(pb, 0), SAL_NUM_BINS - 1);
        int tb = (int)(tmz * 2000.0f);
        tb = min(max(tb, 0), SAL_NUM_BINS - 1);
        atomicAdd(&ph[pb], pin);   // ds_add_f32, random bins -> low conflict
        atomicAdd(&th[tb], tin);
    }
    __syncthreads();

    // per-thread partial sums over bins t, t+256, ...
    float dot = 0.0f, p2 = 0.0f, t2 = 0.0f;
    for (int i = t; i < SAL_NUM_BINS; i += 256) {
        float p = ph[i], q = th[i];
        dot = fmaf(p, q, dot);
        p2  = fmaf(p, p, p2);
        t2  = fmaf(q, q, t2);
    }

    // wave64 shuffle reduction
    for (int off = 32; off > 0; off >>= 1) {
        dot += __shfl_down(dot, off, 64);
        p2  += __shfl_down(p2,  off, 64);
        t2  += __shfl_down(t2,  off, 64);
    }
    __shared__ float rbuf[3][4];
    const int wave = t >> 6;
    const int lane = t & 63;
    if (lane == 0) { rbuf[0][wave] = dot; rbuf[1][wave] = p2; rbuf[2][wave] = t2; }
    __syncthreads();
    if (t == 0) {
        float d = rbuf[0][0] + rbuf[0][1] + rbuf[0][2] + rbuf[0][3];
        float a = rbuf[1][0] + rbuf[1][1] + rbuf[1][2] + rbuf[1][3];
        float c = rbuf[2][0] + rbuf[2][1] + rbuf[2][2] + rbuf[2][3];
        float pn = fmaxf(sqrtf(a), 1e-8f);
        float tn = fmaxf(sqrtf(c), 1e-8f);
        float cs = d / (pn * tn);
        cs = fminf(fmaxf(cs, -1.0f), 1.0f);
        row_angle[b] = acosf(cs) * (float)(1.0 / M_PI);
    }
}

__global__ __launch_bounds__(256) void sal_reduce_kernel(
    const float* __restrict__ row_angle, float* __restrict__ out)
{
    const int t = threadIdx.x;
    float s = 0.0f;
    for (int i = t; i < SAL_B; i += 256) s += row_angle[i];
    for (int off = 32; off > 0; off >>= 1) s += __shfl_down(s, off, 64);
    __shared__ float rbuf[4];
    const int wave = t >> 6;
    const int lane = t & 63;
    if (lane == 0) rbuf[wave] = s;
    __syncthreads();
    if (t == 0) out[0] = (rbuf[0] + rbuf[1] + rbuf[2] + rbuf[3]) * (float)(1.0 / SAL_B);
}

extern "C" void kernel_launch(void* const* d_in, const int* in_sizes, int n_in,
                              void* d_out, int out_size, void* d_ws, size_t ws_size,
                              hipStream_t stream) {
    const float* pred_mz   = (const float*)d_in[0];
    const float* pred_int  = (const float*)d_in[1];
    const float* targ_mz   = (const float*)d_in[2];
    const float* targ_int  = (const float*)d_in[3];
    const float* targ_mask = (const float*)d_in[4];
    float* row_angle = (float*)d_ws;   // 8192 floats, fully overwritten each call
    float* out = (float*)d_out;

    sal_row_kernel<<<SAL_B, 256, 0, stream>>>(pred_mz, pred_int, targ_mz,
                                              targ_int, targ_mask, row_angle);
    sal_reduce_kernel<<<1, 256, 0, stream>>>(row_angle, out);
}

// Round 2
// 112.489 us; speedup vs baseline: 1.0894x; 1.0894x over previous
//
#include <hip/hip_runtime.h>
#include <math.h>

// SpectralAngleLoss: B=8192 rows, N=256 peaks, 2000 bins.
// Kernel 1: 2 rows per block (256 thr). Per-row LDS histograms (pred, targ),
//           float2 global loads, float4 LDS zero/scan -> angle/pi per row.
// Kernel 2: deterministic tree reduction of 8192 row angles -> mean.

#define SAL_NUM_BINS 2000
#define SAL_B 8192
#define SAL_N 256
#define SAL_RPB 2                      // rows per block
#define SAL_BLOCKS (SAL_B / SAL_RPB)   // 4096

__global__ __launch_bounds__(256) void sal_row_kernel(
    const float* __restrict__ pred_mz,
    const float* __restrict__ pred_int,
    const float* __restrict__ targ_mz,
    const float* __restrict__ targ_int,
    const float* __restrict__ targ_mask,
    float* __restrict__ row_angle)
{
    // [row][pred/targ][bin], 32000 B, 16B-aligned for float4 access
    __shared__ __align__(16) float hist[SAL_RPB][2][SAL_NUM_BINS];
    __shared__ float rbuf[SAL_RPB][2][3];  // [row][wave-in-row][dot,p2,t2]
    const int t = threadIdx.x;

    // zero 8000 floats = 2000 float4 across 256 threads (8 iters, last partial)
    {
        float4* h4 = (float4*)&hist[0][0][0];
        const float4 z = make_float4(0.f, 0.f, 0.f, 0.f);
        #pragma unroll
        for (int i = 0; i < 8; ++i) {
            int idx = t + i * 256;
            if (idx < (SAL_RPB * 2 * SAL_NUM_BINS) / 4) h4[idx] = z;
        }
    }
    __syncthreads();

    const int r   = t >> 7;        // row within block (0..1)
    const int u   = t & 127;       // thread within row
    const int row = blockIdx.x * SAL_RPB + r;
    const int base = row * SAL_N;

    // each thread handles 2 consecutive peaks of its row (float2 loads)
    const float2 pmz = ((const float2*)(pred_mz  + base))[u];
    const float2 pin = ((const float2*)(pred_int + base))[u];
    const float2 tmz = ((const float2*)(targ_mz  + base))[u];
    const float2 tin = ((const float2*)(targ_int + base))[u];
    const float2 tms = ((const float2*)(targ_mask+ base))[u];

    int pb0 = min(max((int)(pmz.x * 2000.0f), 0), SAL_NUM_BINS - 1);
    int pb1 = min(max((int)(pmz.y * 2000.0f), 0), SAL_NUM_BINS - 1);
    int tb0 = min(max((int)(tmz.x * 2000.0f), 0), SAL_NUM_BINS - 1);
    int tb1 = min(max((int)(tmz.y * 2000.0f), 0), SAL_NUM_BINS - 1);
    atomicAdd(&hist[r][0][pb0], pin.x);            // ds_add_f32, ~random bins
    atomicAdd(&hist[r][0][pb1], pin.y);
    atomicAdd(&hist[r][1][tb0], tin.x * tms.x);
    atomicAdd(&hist[r][1][tb1], tin.y * tms.y);
    __syncthreads();

    // scan 500 float4 per histogram, 128 threads per row
    const float4* p4 = (const float4*)&hist[r][0][0];
    const float4* q4 = (const float4*)&hist[r][1][0];
    float dot = 0.f, p2 = 0.f, t2 = 0.f;
    for (int i = u; i < SAL_NUM_BINS / 4; i += 128) {
        float4 p = p4[i], q = q4[i];
        dot = fmaf(p.x, q.x, dot); p2 = fmaf(p.x, p.x, p2); t2 = fmaf(q.x, q.x, t2);
        dot = fmaf(p.y, q.y, dot); p2 = fmaf(p.y, p.y, p2); t2 = fmaf(q.y, q.y, t2);
        dot = fmaf(p.z, q.z, dot); p2 = fmaf(p.z, p.z, p2); t2 = fmaf(q.z, q.z, t2);
        dot = fmaf(p.w, q.w, dot); p2 = fmaf(p.w, p.w, p2); t2 = fmaf(q.w, q.w, t2);
    }

    // wave64 shuffle reduction, then combine the row's 2 waves via LDS
    for (int off = 32; off > 0; off >>= 1) {
        dot += __shfl_down(dot, off, 64);
        p2  += __shfl_down(p2,  off, 64);
        t2  += __shfl_down(t2,  off, 64);
    }
    const int wir = (t >> 6) & 1;  // wave index within row
    if ((t & 63) == 0) {
        rbuf[r][wir][0] = dot; rbuf[r][wir][1] = p2; rbuf[r][wir][2] = t2;
    }
    __syncthreads();
    if (u == 0) {
        float d = rbuf[r][0][0] + rbuf[r][1][0];
        float a = rbuf[r][0][1] + rbuf[r][1][1];
        float c = rbuf[r][0][2] + rbuf[r][1][2];
        float pn = fmaxf(sqrtf(a), 1e-8f);
        float tn = fmaxf(sqrtf(c), 1e-8f);
        float cs = d / (pn * tn);
        cs = fminf(fmaxf(cs, -1.0f), 1.0f);
        row_angle[row] = acosf(cs) * (float)(1.0 / M_PI);
    }
}

__global__ __launch_bounds__(256) void sal_reduce_kernel(
    const float* __restrict__ row_angle, float* __restrict__ out)
{
    const int t = threadIdx.x;
    const float4* ra4 = (const float4*)row_angle;
    float s = 0.0f;
    for (int i = t; i < SAL_B / 4; i += 256) {
        float4 v = ra4[i];
        s += (v.x + v.y) + (v.z + v.w);
    }
    for (int off = 32; off > 0; off >>= 1) s += __shfl_down(s, off, 64);
    __shared__ float rbuf[4];
    const int wave = t >> 6;
    if ((t & 63) == 0) rbuf[wave] = s;
    __syncthreads();
    if (t == 0) out[0] = ((rbuf[0] + rbuf[1]) + (rbuf[2] + rbuf[3])) * (float)(1.0 / SAL_B);
}

extern "C" void kernel_launch(void* const* d_in, const int* in_sizes, int n_in,
                              void* d_out, int out_size, void* d_ws, size_t ws_size,
                              hipStream_t stream) {
    const float* pred_mz   = (const float*)d_in[0];
    const float* pred_int  = (const float*)d_in[1];
    const float* targ_mz   = (const float*)d_in[2];
    const float* targ_int  = (const float*)d_in[3];
    const float* targ_mask = (const float*)d_in[4];
    float* row_angle = (float*)d_ws;   // 8192 floats, fully overwritten each call
    float* out = (float*)d_out;

    sal_row_kernel<<<SAL_BLOCKS, 256, 0, stream>>>(pred_mz, pred_int, targ_mz,
                                                   targ_int, targ_mask, row_angle);
    sal_reduce_kernel<<<1, 256, 0, stream>>>(row_angle, out);
}

// Round 3
// 111.443 us; speedup vs baseline: 1.0996x; 1.0094x over previous
//
#include <hip/hip_runtime.h>
#include <math.h>

// SpectralAngleLoss: B=8192 rows, N=256 peaks, 2000 bins.
//
// Key identity: with p[b] = sum_{i: bin_i=b} pin_i (final histogram),
//   dot = sum_b p[b]*q[b]   = sum_i pin_i * q[pbin_i]
//   p2  = sum_b p[b]^2      = sum_i pin_i * p[pbin_i]
//   t2  = sum_b q[b]^2      = sum_j tin_j * q[tbin_j]
// so after the LDS scatter we need only 3 scalar LDS reads per peak —
// no 2000-bin scan. And instead of re-zeroing 16 KB per row, each thread
// writes 0 back to the bins it touched (scatter-undo, idempotent).
//
// Kernel 1: grid 2048 x 256thr, 16 KB LDS -> 8 blocks/CU resident.
//           4 rows per block sequentially; one peak per thread.
// Kernel 2: deterministic reduction of 2048 block partials -> mean.

#define SAL_NUM_BINS 2000
#define SAL_B 8192
#define SAL_N 256
#define SAL_RPB 4                      // rows per block (sequential)
#define SAL_BLOCKS (SAL_B / SAL_RPB)   // 2048

__global__ __launch_bounds__(256) void sal_row_kernel(
    const float* __restrict__ pred_mz,
    const float* __restrict__ pred_int,
    const float* __restrict__ targ_mz,
    const float* __restrict__ targ_int,
    const float* __restrict__ targ_mask,
    float* __restrict__ block_partial)
{
    __shared__ __align__(16) float hist[2][SAL_NUM_BINS];  // [pred/targ][bin]
    __shared__ float rbuf[2][4][3];  // [row parity][wave][dot,p2,t2]
    const int t = threadIdx.x;

    // one-time zero: 4000 floats = 1000 float4 over 256 threads
    {
        float4* h4 = (float4*)&hist[0][0];
        const float4 z = make_float4(0.f, 0.f, 0.f, 0.f);
        #pragma unroll
        for (int i = 0; i < 4; ++i) {
            int idx = t + i * 256;
            if (idx < (2 * SAL_NUM_BINS) / 4) h4[idx] = z;
        }
    }

    // prefetch all rows' peaks (20 dword loads in flight, coalesced)
    float pmz[SAL_RPB], pin[SAL_RPB], tmz[SAL_RPB], tin[SAL_RPB];
    #pragma unroll
    for (int r = 0; r < SAL_RPB; ++r) {
        const int base = (blockIdx.x * SAL_RPB + r) * SAL_N + t;
        pmz[r] = pred_mz[base];
        pin[r] = pred_int[base];
        tmz[r] = targ_mz[base];
        tin[r] = targ_int[base] * targ_mask[base];
    }
    __syncthreads();  // zeros visible before first scatter

    float block_sum = 0.0f;  // meaningful on thread 0 only
    const int wave = t >> 6;

    #pragma unroll
    for (int r = 0; r < SAL_RPB; ++r) {
        const int pb = min(max((int)(pmz[r] * 2000.0f), 0), SAL_NUM_BINS - 1);
        const int tb = min(max((int)(tmz[r] * 2000.0f), 0), SAL_NUM_BINS - 1);

        atomicAdd(&hist[0][pb], pin[r]);      // ds_add_f32, ~random bins
        atomicAdd(&hist[1][tb], tin[r]);
        __syncthreads();                      // scatter complete

        const float pv = hist[0][pb];         // p[pbin]
        const float qv = hist[1][pb];         // q[pbin]
        const float tv = hist[1][tb];         // q[tbin]
        float dot = pin[r] * qv;
        float p2  = pin[r] * pv;
        float t2  = tin[r] * tv;
        __syncthreads();                      // reads complete before undo

        hist[0][pb] = 0.0f;                   // scatter-undo (idempotent)
        hist[1][tb] = 0.0f;

        // wave64 shuffle reduction of the 3 partials
        #pragma unroll
        for (int off = 32; off > 0; off >>= 1) {
            dot += __shfl_down(dot, off, 64);
            p2  += __shfl_down(p2,  off, 64);
            t2  += __shfl_down(t2,  off, 64);
        }
        if ((t & 63) == 0) {
            rbuf[r & 1][wave][0] = dot;
            rbuf[r & 1][wave][1] = p2;
            rbuf[r & 1][wave][2] = t2;
        }
        __syncthreads();                      // undo + rbuf visible

        if (t == 0) {
            float d = (rbuf[r & 1][0][0] + rbuf[r & 1][1][0]) +
                      (rbuf[r & 1][2][0] + rbuf[r & 1][3][0]);
            float a = (rbuf[r & 1][0][1] + rbuf[r & 1][1][1]) +
                      (rbuf[r & 1][2][1] + rbuf[r & 1][3][1]);
            float c = (rbuf[r & 1][0][2] + rbuf[r & 1][1][2]) +
                      (rbuf[r & 1][2][2] + rbuf[r & 1][3][2]);
            float pn = fmaxf(sqrtf(a), 1e-8f);
            float tn = fmaxf(sqrtf(c), 1e-8f);
            float cs = d / (pn * tn);
            cs = fminf(fmaxf(cs, -1.0f), 1.0f);
            block_sum += acosf(cs) * (float)(1.0 / M_PI);
        }
    }
    if (t == 0) block_partial[blockIdx.x] = block_sum;
}

__global__ __launch_bounds__(256) void sal_reduce_kernel(
    const float* __restrict__ block_partial, float* __restrict__ out)
{
    const int t = threadIdx.x;
    const float4* bp4 = (const float4*)block_partial;
    float s = 0.0f;
    #pragma unroll
    for (int i = 0; i < SAL_BLOCKS / 4 / 256; ++i) {   // 2048/4 = 512 float4
        float4 v = bp4[t + i * 256];
        s += (v.x + v.y) + (v.z + v.w);
    }
    #pragma unroll
    for (int off = 32; off > 0; off >>= 1) s += __shfl_down(s, off, 64);
    __shared__ float rbuf[4];
    if ((t & 63) == 0) rbuf[t >> 6] = s;
    __syncthreads();
    if (t == 0) out[0] = ((rbuf[0] + rbuf[1]) + (rbuf[2] + rbuf[3])) * (float)(1.0 / SAL_B);
}

extern "C" void kernel_launch(void* const* d_in, const int* in_sizes, int n_in,
                              void* d_out, int out_size, void* d_ws, size_t ws_size,
                              hipStream_t stream) {
    const float* pred_mz   = (const float*)d_in[0];
    const float* pred_int  = (const float*)d_in[1];
    const float* targ_mz   = (const float*)d_in[2];
    const float* targ_int  = (const float*)d_in[3];
    const float* targ_mask = (const float*)d_in[4];
    float* block_partial = (float*)d_ws;   // 2048 floats, fully overwritten
    float* out = (float*)d_out;

    sal_row_kernel<<<SAL_BLOCKS, 256, 0, stream>>>(pred_mz, pred_int, targ_mz,
                                                   targ_int, targ_mask, block_partial);
    sal_reduce_kernel<<<1, 256, 0, stream>>>(block_partial, out);
}